// Round 4
// baseline (1460.645 us; speedup 1.0000x reference)
//
#include <hip/hip_runtime.h>
#include <math.h>

#define BSZ 32
#define NI  128

typedef __attribute__((ext_vector_type(8))) _Float16 f16x8;
typedef __attribute__((ext_vector_type(4))) _Float16 f16x4;
typedef __attribute__((ext_vector_type(4))) float    f32x4;

// Verified convention (R2/R3 working kernels):
//   MFMA16(X, Y, C): C[row = quad*4+reg <- X's l15-index][col = l15 <- Y's l15-index]
//   X,Y k-index = quad*8 + j (j=0..7), i.e. frag = &buf[(idx15)*stride + ks*32 + quad*8]
#define MFMA16(a, b, c) __builtin_amdgcn_mfma_f32_16x16x32_f16((a), (b), (c), 0, 0, 0)

__device__ inline float dot4f(float4 a, float4 b) {
    return a.x * b.x + a.y * b.y + a.z * b.z + a.w * b.w;
}

// ---------------------------------------------------------------------------
// tokens f32 -> f16
// ---------------------------------------------------------------------------
__global__ __launch_bounds__(256) void tok_convert(const float* __restrict__ in,
                                                   _Float16* __restrict__ out)
{
    const int n4 = (BSZ * 2048 * 256) / 4;
    for (int i = blockIdx.x * 256 + threadIdx.x; i < n4; i += gridDim.x * 256) {
        float4 v = ((const float4*)in)[i];
        f16x4 h;
        h[0] = (_Float16)v.x; h[1] = (_Float16)v.y;
        h[2] = (_Float16)v.z; h[3] = (_Float16)v.w;
        ((f16x4*)out)[i] = h;
    }
}

// ---------------------------------------------------------------------------
// 64x64 f32->f16 transpose tile through LDS (coalesced both sides)
// ---------------------------------------------------------------------------
__device__ inline void tpose64(const float* __restrict__ src, int Csrc,
                               _Float16* __restrict__ dst, int Rsrc,
                               int r0, int c0, _Float16 (*tbuf)[72], int tid)
{
#pragma unroll
    for (int it = 0; it < 4; it++) {
        int idx = tid + it * 256;
        int rr = idx >> 4, c4 = idx & 15;
        float4 w = *(const float4*)(src + (size_t)(r0 + rr) * Csrc + c0 + c4 * 4);
        tbuf[c4 * 4 + 0][rr] = (_Float16)w.x;
        tbuf[c4 * 4 + 1][rr] = (_Float16)w.y;
        tbuf[c4 * 4 + 2][rr] = (_Float16)w.z;
        tbuf[c4 * 4 + 3][rr] = (_Float16)w.w;
    }
    __syncthreads();
#pragma unroll
    for (int it = 0; it < 2; it++) {
        int idx = tid + it * 256;
        int orr = idx >> 3, oc = idx & 7;
        *(f16x8*)(dst + (size_t)(c0 + orr) * Rsrc + r0 + oc * 8) = *(const f16x8*)&tbuf[orr][oc * 8];
    }
}

// ---------------------------------------------------------------------------
// prep: transposed f16 weights, qn, cls_n, qint2 = q@Wqi + bqi + bqs
// blocks 0..111 transposes | 112..239 intents | 240..271 cls
// ---------------------------------------------------------------------------
__global__ __launch_bounds__(256) void prep(
    const float* __restrict__ Wk, const float* __restrict__ Wv,
    const float* __restrict__ Wqs, const float* __restrict__ Wf1,
    const float* __restrict__ Wf2,
    const float* __restrict__ intent_q, const float* __restrict__ Wqi,
    const float* __restrict__ bqi, const float* __restrict__ bqs,
    const float* __restrict__ cls_embed,
    _Float16* __restrict__ wkT, _Float16* __restrict__ wvT,
    _Float16* __restrict__ wqsT, _Float16* __restrict__ wf1T,
    _Float16* __restrict__ wf2T,
    float* __restrict__ qint2, float* __restrict__ qn, float* __restrict__ clsn)
{
    __shared__ _Float16 tbuf[64][72];
    __shared__ float buf[256];
    __shared__ float red[4];
    const int t = threadIdx.x, blk = blockIdx.x;
    const int lane = t & 63, w = t >> 6;

    if (blk < 112) {
        if (blk < 16)       tpose64(Wk, 256, wkT, 256, (blk >> 2) * 64, (blk & 3) * 64, tbuf, t);
        else if (blk < 32)  { int tt = blk - 16; tpose64(Wv, 256, wvT, 256, (tt >> 2) * 64, (tt & 3) * 64, tbuf, t); }
        else if (blk < 48)  { int tt = blk - 32; tpose64(Wqs, 256, wqsT, 256, (tt >> 2) * 64, (tt & 3) * 64, tbuf, t); }
        else if (blk < 80)  { int tt = blk - 48; tpose64(Wf1, 512, wf1T, 256, (tt & 3) * 64, (tt >> 2) * 64, tbuf, t); }
        else                { int tt = blk - 80; tpose64(Wf2, 256, wf2T, 512, (tt >> 2) * 64, (tt & 3) * 64, tbuf, t); }
    } else if (blk < 240) {
        int i = blk - 112;
        float x = intent_q[(size_t)i * 256 + t];
        buf[t] = x;
        float ss = x * x;
#pragma unroll
        for (int m = 1; m < 64; m <<= 1) ss += __shfl_xor(ss, m, 64);
        if (lane == 0) red[w] = ss;
        __syncthreads();
        float tot = red[0] + red[1] + red[2] + red[3];
        qn[(size_t)i * 256 + t] = x / fmaxf(sqrtf(tot), 1e-12f);
        float acc = bqi[t] + bqs[t];
        for (int e = 0; e < 256; e += 4) {
            const float4 q4 = *(const float4*)&buf[e];
            acc += q4.x * Wqi[(size_t)(e + 0) * 256 + t];
            acc += q4.y * Wqi[(size_t)(e + 1) * 256 + t];
            acc += q4.z * Wqi[(size_t)(e + 2) * 256 + t];
            acc += q4.w * Wqi[(size_t)(e + 3) * 256 + t];
        }
        qint2[(size_t)i * 256 + t] = acc;
    } else {
        int b = blk - 240;
        float x = cls_embed[(size_t)b * 256 + t];
        float ss = x * x;
#pragma unroll
        for (int m = 1; m < 64; m <<= 1) ss += __shfl_xor(ss, m, 64);
        if (lane == 0) red[w] = ss;
        __syncthreads();
        float tot = red[0] + red[1] + red[2] + red[3];
        clsn[(size_t)b * 256 + t] = x / fmaxf(sqrtf(tot), 1e-12f);
    }
}

// ---------------------------------------------------------------------------
// k = tok@Wk + bk -> k16[b][s][d]   (m=d via A=wkT, n=s via B=tok)
// ---------------------------------------------------------------------------
__global__ __launch_bounds__(64) void k_proj(
    const _Float16* __restrict__ tok, const _Float16* __restrict__ wkT,
    const float* __restrict__ bk, _Float16* __restrict__ k16)
{
    const int lane = threadIdx.x, l15 = lane & 15, quad = lane >> 4;
    const int blk = blockIdx.x;
    const int b = blk >> 6, mp = (blk >> 3) & 7, se = blk & 7;
    const _Float16* tb = tok + (size_t)b * 2048 * 256;

    f16x8 a0[8], a1[8];
#pragma unroll
    for (int ks = 0; ks < 8; ks++) {
        a0[ks] = *(const f16x8*)(wkT + (size_t)(mp * 32 + l15) * 256 + ks * 32 + quad * 8);
        a1[ks] = *(const f16x8*)(wkT + (size_t)(mp * 32 + 16 + l15) * 256 + ks * 32 + quad * 8);
    }
    f32x4 bi0 = *(const f32x4*)(bk + mp * 32 + quad * 4);
    f32x4 bi1 = *(const f32x4*)(bk + mp * 32 + 16 + quad * 4);

    for (int nt = 0; nt < 16; nt++) {
        int s = se * 256 + nt * 16 + l15;
        f32x4 c0 = {0.f, 0.f, 0.f, 0.f}, c1 = {0.f, 0.f, 0.f, 0.f};
#pragma unroll
        for (int ks = 0; ks < 8; ks++) {
            f16x8 bf = *(const f16x8*)(tb + (size_t)s * 256 + ks * 32 + quad * 8);
            c0 = MFMA16(a0[ks], bf, c0);
            c1 = MFMA16(a1[ks], bf, c1);
        }
        f16x4 p0, p1;
#pragma unroll
        for (int reg = 0; reg < 4; reg++) {
            p0[reg] = (_Float16)(c0[reg] + bi0[reg]);
            p1[reg] = (_Float16)(c1[reg] + bi1[reg]);
        }
        _Float16* kp = k16 + ((size_t)b * 2048 + s) * 256 + mp * 32 + quad * 4;
        *(f16x4*)kp = p0;
        *(f16x4*)(kp + 16) = p1;
    }
}

// ---------------------------------------------------------------------------
// v = tok@Wv + bv -> vT16[b][d][s]   (m=s via A=tok, n=d via B=wvT)
// ---------------------------------------------------------------------------
__global__ __launch_bounds__(64) void v_proj(
    const _Float16* __restrict__ tok, const _Float16* __restrict__ wvT,
    const float* __restrict__ bv, _Float16* __restrict__ vT16)
{
    const int lane = threadIdx.x, l15 = lane & 15, quad = lane >> 4;
    const int blk = blockIdx.x;
    const int b = blk >> 6, sp = blk & 63;
    const _Float16* tb = tok + (size_t)b * 2048 * 256;

    f16x8 a0[8], a1[8];
#pragma unroll
    for (int ks = 0; ks < 8; ks++) {
        a0[ks] = *(const f16x8*)(tb + (size_t)(sp * 32 + l15) * 256 + ks * 32 + quad * 8);
        a1[ks] = *(const f16x8*)(tb + (size_t)(sp * 32 + 16 + l15) * 256 + ks * 32 + quad * 8);
    }
    for (int nt = 0; nt < 16; nt++) {
        int d = nt * 16 + l15;
        f32x4 c0 = {0.f, 0.f, 0.f, 0.f}, c1 = {0.f, 0.f, 0.f, 0.f};
#pragma unroll
        for (int ks = 0; ks < 8; ks++) {
            f16x8 bf = *(const f16x8*)(wvT + (size_t)d * 256 + ks * 32 + quad * 8);
            c0 = MFMA16(a0[ks], bf, c0);
            c1 = MFMA16(a1[ks], bf, c1);
        }
        float bb = bv[d];
        f16x4 p0, p1;
#pragma unroll
        for (int reg = 0; reg < 4; reg++) {
            p0[reg] = (_Float16)(c0[reg] + bb);
            p1[reg] = (_Float16)(c1[reg] + bb);
        }
        _Float16* vp = vT16 + ((size_t)b * 256 + d) * 2048 + sp * 32 + quad * 4;
        *(f16x4*)vp = p0;
        *(f16x4*)(vp + 16) = p1;
    }
}

// ---------------------------------------------------------------------------
// slots init: slots[b][r][d] = mu[n] + noise[i][b][n]*sigma[n], r = i*4+n
// ---------------------------------------------------------------------------
__global__ __launch_bounds__(256) void slots_init(
    const float* __restrict__ noise, const float* __restrict__ slot_mu,
    const float* __restrict__ slot_sigma, float* __restrict__ slots)
{
    int e4 = blockIdx.x * 256 + threadIdx.x;     // 0..1048575 f32x4 units
    int d4 = e4 & 63;
    int r  = (e4 >> 6) & 511;
    int b  = e4 >> 15;
    int i = r >> 2, n = r & 3;
    float4 mu = *(const float4*)(slot_mu + n * 256 + d4 * 4);
    float4 sg = *(const float4*)(slot_sigma + n * 256 + d4 * 4);
    float4 ns = *(const float4*)(noise + (((size_t)i * BSZ + b) * 4 + n) * 256 + d4 * 4);
    float4 o;
    o.x = mu.x + ns.x * sg.x; o.y = mu.y + ns.y * sg.y;
    o.z = mu.z + ns.z * sg.z; o.w = mu.w + ns.w * sg.w;
    *(float4*)(slots + (size_t)e4 * 4) = o;
}

// ---------------------------------------------------------------------------
// qslot: qs16 = (slots@Wqs + qint2) * (1/16), f16.  m=d (A=wqsT), n=rows.
// grid 512: rb = bx>>1 (64 rows), dh = bx&1 (128-d half)
// ---------------------------------------------------------------------------
__global__ __launch_bounds__(256) void qslot_k(
    const float* __restrict__ slots, const _Float16* __restrict__ wqsT,
    const float* __restrict__ qint2, _Float16* __restrict__ qs16)
{
    const int tid = threadIdx.x, lane = tid & 63, wv = tid >> 6;
    const int l15 = lane & 15, quad = lane >> 4;
    const int bx = blockIdx.x, rb = bx >> 1, dh = bx & 1;
    const int gr = rb * 64 + wv * 16 + l15;

    f16x8 bs[8];
    const float* sp = slots + (size_t)gr * 256 + quad * 8;
#pragma unroll
    for (int ks = 0; ks < 8; ks++) {
        float4 a = *(const float4*)(sp + ks * 32);
        float4 b = *(const float4*)(sp + ks * 32 + 4);
        f16x8 h;
        h[0] = (_Float16)a.x; h[1] = (_Float16)a.y; h[2] = (_Float16)a.z; h[3] = (_Float16)a.w;
        h[4] = (_Float16)b.x; h[5] = (_Float16)b.y; h[6] = (_Float16)b.z; h[7] = (_Float16)b.w;
        bs[ks] = h;
    }
    const int iq = (gr & 511) >> 2;
#pragma unroll
    for (int dt = 0; dt < 8; dt++) {
        f32x4 c = {0.f, 0.f, 0.f, 0.f};
#pragma unroll
        for (int ks = 0; ks < 8; ks++)
            c = MFMA16(*(const f16x8*)(wqsT + (size_t)(dh * 128 + dt * 16 + l15) * 256 + ks * 32 + quad * 8), bs[ks], c);
        int d0 = dh * 128 + dt * 16 + quad * 4;
        float4 qi = *(const float4*)(qint2 + (size_t)iq * 256 + d0);
        f16x4 o;
#pragma unroll
        for (int reg = 0; reg < 4; reg++) o[reg] = (_Float16)((c[reg] + qi[reg]) * 0.0625f);
        *(f16x4*)(qs16 + (size_t)gr * 256 + d0) = o;
    }
}

// ---------------------------------------------------------------------------
// logits + exp: P[b][r][s'] = exp(qs·k), psum partials. m=s (A=k16), n=rows.
// grid 1024 per half: b = bx&31, rb = (bx>>5)&7, sb = bx>>8 (4 x 256-s)
// ---------------------------------------------------------------------------
__global__ __launch_bounds__(256) void logits_k(
    const _Float16* __restrict__ qs16, const _Float16* __restrict__ k16,
    _Float16* __restrict__ P, float* __restrict__ psum, int half)
{
    const int tid = threadIdx.x, lane = tid & 63, wv = tid >> 6;
    const int l15 = lane & 15, quad = lane >> 4;
    const int bx = blockIdx.x;
    const int b = bx & 31, rb = (bx >> 5) & 7, sb = bx >> 8;
    const int r0 = rb * 64 + wv * 16;
    const int gr0 = b * 512 + r0;
    const int s0g = half * 1024 + sb * 256;
    const int s0l = sb * 256;

    f16x8 bq[8];
#pragma unroll
    for (int ks = 0; ks < 8; ks++)
        bq[ks] = *(const f16x8*)(qs16 + (size_t)(gr0 + l15) * 256 + ks * 32 + quad * 8);

    float rsum = 0.f;
    _Float16* Pr = P + (size_t)(gr0 + l15) * 1024 + s0l + quad * 4;
    const _Float16* kb = k16 + ((size_t)b * 2048 + s0g + l15) * 256 + quad * 8;
#pragma unroll 2
    for (int mt = 0; mt < 16; mt++) {
        f32x4 c = {0.f, 0.f, 0.f, 0.f};
#pragma unroll
        for (int ks = 0; ks < 8; ks++)
            c = MFMA16(*(const f16x8*)(kb + (size_t)mt * 16 * 256 + ks * 32), bq[ks], c);
        f16x4 o;
#pragma unroll
        for (int reg = 0; reg < 4; reg++) {
            float p = __expf(fminf(c[reg], 10.5f));   // clamp: keep f16-finite; logits ~ +-2
            rsum += p;
            o[reg] = (_Float16)p;
        }
        *(f16x4*)(Pr + mt * 16) = o;
    }
    rsum += __shfl_xor(rsum, 16, 64);
    rsum += __shfl_xor(rsum, 32, 64);
    if (quad == 0) psum[(size_t)(gr0 + l15) * 8 + half * 4 + sb] = rsum;
}

// ---------------------------------------------------------------------------
// PV: O += P @ v  (K=1024 per half). m=d (A=vT16), n=rows (B=P).
// grid 512: b = bx&31, rb = (bx>>5)&7, dh = bx>>8
// ---------------------------------------------------------------------------
__global__ __launch_bounds__(256) void pv_k(
    const _Float16* __restrict__ P, const _Float16* __restrict__ vT16,
    float* __restrict__ O, int half, int accum)
{
    const int tid = threadIdx.x, lane = tid & 63, wv = tid >> 6;
    const int l15 = lane & 15, quad = lane >> 4;
    const int bx = blockIdx.x;
    const int b = bx & 31, rb = (bx >> 5) & 7, dh = bx >> 8;
    const int gr = b * 512 + rb * 64 + wv * 16 + l15;

    f32x4 c[8];
    if (accum) {
#pragma unroll
        for (int dt = 0; dt < 8; dt++)
            c[dt] = *(const f32x4*)(O + (size_t)gr * 256 + dh * 128 + dt * 16 + quad * 4);
    } else {
#pragma unroll
        for (int dt = 0; dt < 8; dt++) c[dt] = (f32x4){0.f, 0.f, 0.f, 0.f};
    }
    const _Float16* Pp = P + (size_t)gr * 1024 + quad * 8;
    const _Float16* vb = vT16 + ((size_t)b * 256 + dh * 128 + l15) * 2048 + half * 1024 + quad * 8;
    for (int ks = 0; ks < 32; ks++) {
        f16x8 pf = *(const f16x8*)(Pp + ks * 32);
#pragma unroll
        for (int dt = 0; dt < 8; dt++)
            c[dt] = MFMA16(*(const f16x8*)(vb + (size_t)dt * 16 * 2048 + ks * 32), pf, c[dt]);
    }
#pragma unroll
    for (int dt = 0; dt < 8; dt++)
        *(f32x4*)(O + (size_t)gr * 256 + dh * 128 + dt * 16 + quad * 4) = c[dt];
}

// ---------------------------------------------------------------------------
// LN: y = slots + O/l; x1 = LN1(y) -> slots; h16 = LN2(x1). wave per row.
// ---------------------------------------------------------------------------
__global__ __launch_bounds__(256) void ln_k(
    const float* __restrict__ O, const float* __restrict__ psum,
    float* __restrict__ slots, _Float16* __restrict__ h16,
    const float* __restrict__ ln1_g, const float* __restrict__ ln1_b,
    const float* __restrict__ ln2_g, const float* __restrict__ ln2_b)
{
    const int tid = threadIdx.x, lane = tid & 63, wv = tid >> 6;
    const int row = blockIdx.x * 4 + wv;
    float l = 0.f;
#pragma unroll
    for (int j = 0; j < 8; j++) l += psum[(size_t)row * 8 + j];
    float invl = 1.f / l;
    float4 o4 = *(const float4*)(O + (size_t)row * 256 + lane * 4);
    float4 s4 = *(const float4*)(slots + (size_t)row * 256 + lane * 4);
    float4 y;
    y.x = s4.x + o4.x * invl; y.y = s4.y + o4.y * invl;
    y.z = s4.z + o4.z * invl; y.w = s4.w + o4.w * invl;

    float sm = y.x + y.y + y.z + y.w, sq = dot4f(y, y);
#pragma unroll
    for (int m = 1; m < 64; m <<= 1) { sm += __shfl_xor(sm, m, 64); sq += __shfl_xor(sq, m, 64); }
    float mean = sm * (1.f / 256.f);
    float rstd = rsqrtf(sq * (1.f / 256.f) - mean * mean + 1e-5f);
    float4 g1 = *(const float4*)(ln1_g + lane * 4);
    float4 b1 = *(const float4*)(ln1_b + lane * 4);
    float4 x1;
    x1.x = (y.x - mean) * rstd * g1.x + b1.x;
    x1.y = (y.y - mean) * rstd * g1.y + b1.y;
    x1.z = (y.z - mean) * rstd * g1.z + b1.z;
    x1.w = (y.w - mean) * rstd * g1.w + b1.w;
    *(float4*)(slots + (size_t)row * 256 + lane * 4) = x1;

    float sm2 = x1.x + x1.y + x1.z + x1.w, sq2 = dot4f(x1, x1);
#pragma unroll
    for (int m = 1; m < 64; m <<= 1) { sm2 += __shfl_xor(sm2, m, 64); sq2 += __shfl_xor(sq2, m, 64); }
    float mean2 = sm2 * (1.f / 256.f);
    float rstd2 = rsqrtf(sq2 * (1.f / 256.f) - mean2 * mean2 + 1e-5f);
    float4 g2 = *(const float4*)(ln2_g + lane * 4);
    float4 b2 = *(const float4*)(ln2_b + lane * 4);
    f16x4 h;
    h[0] = (_Float16)((x1.x - mean2) * rstd2 * g2.x + b2.x);
    h[1] = (_Float16)((x1.y - mean2) * rstd2 * g2.y + b2.y);
    h[2] = (_Float16)((x1.z - mean2) * rstd2 * g2.z + b2.z);
    h[3] = (_Float16)((x1.w - mean2) * rstd2 * g2.w + b2.w);
    *(f16x4*)(h16 + (size_t)row * 256 + lane * 4) = h;
}

// ---------------------------------------------------------------------------
// FFN1: act16 = gelu(h16 @ Wf1 + bf1). m=hc (A=wf1T), n=rows.
// grid 512: rb = bx>>1, hh = bx&1 (256-col half)
// ---------------------------------------------------------------------------
__global__ __launch_bounds__(256) void ffn1_k(
    const _Float16* __restrict__ h16, const _Float16* __restrict__ wf1T,
    const float* __restrict__ bf1, _Float16* __restrict__ act16)
{
    const int tid = threadIdx.x, lane = tid & 63, wv = tid >> 6;
    const int l15 = lane & 15, quad = lane >> 4;
    const int bx = blockIdx.x, rb = bx >> 1, hh = bx & 1;
    const int gr = rb * 64 + wv * 16 + l15;

    f16x8 bh[8];
#pragma unroll
    for (int ks = 0; ks < 8; ks++)
        bh[ks] = *(const f16x8*)(h16 + (size_t)gr * 256 + ks * 32 + quad * 8);
#pragma unroll 2
    for (int ht = 0; ht < 16; ht++) {
        f32x4 c = {0.f, 0.f, 0.f, 0.f};
#pragma unroll
        for (int ks = 0; ks < 8; ks++)
            c = MFMA16(*(const f16x8*)(wf1T + (size_t)(hh * 256 + ht * 16 + l15) * 256 + ks * 32 + quad * 8), bh[ks], c);
        int hc0 = hh * 256 + ht * 16 + quad * 4;
        float4 bb = *(const float4*)(bf1 + hc0);
        f16x4 o;
#pragma unroll
        for (int reg = 0; reg < 4; reg++) {
            float xg = c[reg] + bb[reg];
            o[reg] = (_Float16)(0.5f * xg * (1.f + erff(xg * 0.70710678118654752f)));
        }
        *(f16x4*)(act16 + (size_t)gr * 512 + hc0) = o;
    }
}

// ---------------------------------------------------------------------------
// FFN2: slots = x1 + act16 @ Wf2 + bf2. m=d (A=wf2T), n=rows.
// grid 512: rb = bx>>1, dh = bx&1
// ---------------------------------------------------------------------------
__global__ __launch_bounds__(256) void ffn2_k(
    const _Float16* __restrict__ act16, const _Float16* __restrict__ wf2T,
    const float* __restrict__ bf2, float* __restrict__ slots)
{
    const int tid = threadIdx.x, lane = tid & 63, wv = tid >> 6;
    const int l15 = lane & 15, quad = lane >> 4;
    const int bx = blockIdx.x, rb = bx >> 1, dh = bx & 1;
    const int gr = rb * 64 + wv * 16 + l15;

    f32x4 c[8];
#pragma unroll
    for (int dt = 0; dt < 8; dt++) {
        int d0 = dh * 128 + dt * 16 + quad * 4;
        float4 x4 = *(const float4*)(slots + (size_t)gr * 256 + d0);
        float4 bb = *(const float4*)(bf2 + d0);
        c[dt] = (f32x4){x4.x + bb.x, x4.y + bb.y, x4.z + bb.z, x4.w + bb.w};
    }
    const _Float16* ap = act16 + (size_t)gr * 512 + quad * 8;
    for (int ks = 0; ks < 16; ks++) {
        f16x8 bfrag = *(const f16x8*)(ap + ks * 32);
#pragma unroll
        for (int dt = 0; dt < 8; dt++)
            c[dt] = MFMA16(*(const f16x8*)(wf2T + (size_t)(dh * 128 + dt * 16 + l15) * 512 + ks * 32 + quad * 8), bfrag, c[dt]);
    }
#pragma unroll
    for (int dt = 0; dt < 8; dt++)
        *(f32x4*)(slots + (size_t)gr * 256 + dh * 128 + dt * 16 + quad * 4) = c[dt];
}

// ---------------------------------------------------------------------------
// final scoring: wave per (b, i)
// ---------------------------------------------------------------------------
__global__ __launch_bounds__(256) void final_k(
    const float* __restrict__ slots, const float* __restrict__ qn,
    const float* __restrict__ clsn,
    const float* __restrict__ alphap, const float* __restrict__ tempp,
    float* __restrict__ out)
{
    const int tid = threadIdx.x, lane = tid & 63, wv = tid >> 6;
    const int bx = blockIdx.x;
    const int b = bx & 31, ig = bx >> 5;
    const int i = ig * 4 + wv;

    float4 qv = *(const float4*)(qn + (size_t)i * 256 + lane * 4);
    float4 xs[4];
    float st4[4];
#pragma unroll
    for (int n = 0; n < 4; n++) {
        xs[n] = *(const float4*)(slots + ((size_t)b * 512 + i * 4 + n) * 256 + lane * 4);
        float ss = dot4f(xs[n], xs[n]);
        float sq = dot4f(xs[n], qv);
#pragma unroll
        for (int m = 1; m < 64; m <<= 1) { ss += __shfl_xor(ss, m, 64); sq += __shfl_xor(sq, m, 64); }
        st4[n] = sq / fmaxf(sqrtf(ss), 1e-12f);
    }
    float mx = fmaxf(fmaxf(st4[0], st4[1]), fmaxf(st4[2], st4[3]));
    float e0 = __expf(st4[0] - mx), e1 = __expf(st4[1] - mx);
    float e2 = __expf(st4[2] - mx), e3 = __expf(st4[3] - mx);
    float inv = 1.f / (e0 + e1 + e2 + e3);
    float4 smv;
    smv.x = (e0 * xs[0].x + e1 * xs[1].x + e2 * xs[2].x + e3 * xs[3].x) * inv;
    smv.y = (e0 * xs[0].y + e1 * xs[1].y + e2 * xs[2].y + e3 * xs[3].y) * inv;
    smv.z = (e0 * xs[0].z + e1 * xs[1].z + e2 * xs[2].z + e3 * xs[3].z) * inv;
    smv.w = (e0 * xs[0].w + e1 * xs[1].w + e2 * xs[2].w + e3 * xs[3].w) * inv;
    float ssm = dot4f(smv, smv);
    float sqn = dot4f(smv, qv);
    float4 cv = *(const float4*)(clsn + (size_t)b * 256 + lane * 4);
    float cq = dot4f(cv, qv);
#pragma unroll
    for (int m = 1; m < 64; m <<= 1) {
        ssm += __shfl_xor(ssm, m, 64);
        sqn += __shfl_xor(sqn, m, 64);
        cq  += __shfl_xor(cq,  m, 64);
    }
    if (lane == 0) {
        float score = cq + alphap[0] * sqn / fmaxf(sqrtf(ssm), 1e-12f);
        out[(size_t)b * NI + i] = score / fmaxf(tempp[0], 1e-4f);
    }
}

// ---------------------------------------------------------------------------
extern "C" void kernel_launch(void* const* d_in, const int* in_sizes, int n_in,
                              void* d_out, int out_size, void* d_ws, size_t ws_size,
                              hipStream_t stream)
{
    const float* tokens     = (const float*)d_in[0];
    const float* cls_embed  = (const float*)d_in[1];
    const float* intent_q   = (const float*)d_in[2];
    const float* noise      = (const float*)d_in[3];
    const float* Wk  = (const float*)d_in[4];
    const float* bk  = (const float*)d_in[5];
    const float* Wv  = (const float*)d_in[6];
    const float* bv  = (const float*)d_in[7];
    const float* Wqs = (const float*)d_in[8];
    const float* bqs = (const float*)d_in[9];
    const float* Wqi = (const float*)d_in[10];
    const float* bqi = (const float*)d_in[11];
    const float* ln1g = (const float*)d_in[12];
    const float* ln1b = (const float*)d_in[13];
    const float* ln2g = (const float*)d_in[14];
    const float* ln2b = (const float*)d_in[15];
    const float* Wf1 = (const float*)d_in[16];
    const float* bf1 = (const float*)d_in[17];
    const float* Wf2 = (const float*)d_in[18];
    const float* bf2 = (const float*)d_in[19];
    const float* slot_mu    = (const float*)d_in[20];
    const float* slot_sigma = (const float*)d_in[21];
    const float* alphap = (const float*)d_in[22];
    const float* tempp  = (const float*)d_in[23];
    float* out = (float*)d_out;

    char* base = (char*)d_ws;
    // region A (33.5 MB): tok16 during projection; later qs16 | O | h16
    _Float16* tok16 = (_Float16*)(base);
    _Float16* qs16  = (_Float16*)(base);                        //  8388608 B
    float*    O     = (float*)(base + 8388608u);                // 16777216 B
    _Float16* h16   = (_Float16*)(base + 25165824u);            //  8388608 B
    _Float16* k16   = (_Float16*)(base + 33554432u);            // 33554432 B
    _Float16* vT16  = (_Float16*)(base + 67108864u);            // 33554432 B
    _Float16* P     = (_Float16*)(base + 100663296u);           // 33554432 B (aliases act16)
    _Float16* act16 = (_Float16*)(base + 100663296u);           // 16777216 B
    float* slots    = (float*)(base + 134217728u);              // 16777216 B
    _Float16* wkT   = (_Float16*)(base + 150994944u);           //   131072 B
    _Float16* wvT   = (_Float16*)(base + 151126016u);
    _Float16* wqsT  = (_Float16*)(base + 151257088u);
    _Float16* wf1T  = (_Float16*)(base + 151388160u);           //   262144 B
    _Float16* wf2T  = (_Float16*)(base + 151650304u);           //   262144 B
    float* qint2    = (float*)(base + 151912448u);              //   131072 B
    float* qnb      = (float*)(base + 152043520u);              //   131072 B
    float* clsn     = (float*)(base + 152174592u);              //    32768 B
    float* psum     = (float*)(base + 152207360u);              //   524288 B

    tok_convert<<<2048, 256, 0, stream>>>(tokens, tok16);
    prep<<<272, 256, 0, stream>>>(Wk, Wv, Wqs, Wf1, Wf2, intent_q, Wqi, bqi, bqs,
                                  cls_embed, wkT, wvT, wqsT, wf1T, wf2T,
                                  qint2, qnb, clsn);
    k_proj<<<2048, 64, 0, stream>>>(tok16, wkT, bk, k16);
    v_proj<<<2048, 64, 0, stream>>>(tok16, wvT, bv, vT16);
    slots_init<<<4096, 256, 0, stream>>>(noise, slot_mu, slot_sigma, slots);

    for (int it = 0; it < 3; it++) {
        qslot_k<<<512, 256, 0, stream>>>(slots, wqsT, qint2, qs16);
        logits_k<<<1024, 256, 0, stream>>>(qs16, k16, P, psum, 0);
        pv_k<<<512, 256, 0, stream>>>(P, vT16, O, 0, 0);
        logits_k<<<1024, 256, 0, stream>>>(qs16, k16, P, psum, 1);
        pv_k<<<512, 256, 0, stream>>>(P, vT16, O, 1, 1);
        ln_k<<<4096, 256, 0, stream>>>(O, psum, slots, h16, ln1g, ln1b, ln2g, ln2b);
        ffn1_k<<<512, 256, 0, stream>>>(h16, wf1T, bf1, act16);
        ffn2_k<<<512, 256, 0, stream>>>(act16, wf2T, bf2, slots);
    }
    final_k<<<1024, 256, 0, stream>>>(slots, qnb, clsn, alphap, tempp, out);
}

// Round 5
// 1430.219 us; speedup vs baseline: 1.0213x; 1.0213x over previous
//
#include <hip/hip_runtime.h>
#include <math.h>

#define BSZ 32
#define NI  128

typedef __attribute__((ext_vector_type(8))) _Float16 f16x8;
typedef __attribute__((ext_vector_type(4))) _Float16 f16x4;
typedef __attribute__((ext_vector_type(4))) float    f32x4;

// Verified convention (R2-R4 working kernels):
//   MFMA16(X, Y, C): C[row = quad*4+reg <- X's l15-index][col = l15 <- Y's l15-index]
//   X,Y k-index = quad*8 + j, i.e. frag = &buf[(idx15)*stride + ks*32 + quad*8]
#define MFMA16(a, b, c) __builtin_amdgcn_mfma_f32_16x16x32_f16((a), (b), (c), 0, 0, 0)

__device__ inline float dot4f(float4 a, float4 b) {
    return a.x * b.x + a.y * b.y + a.z * b.z + a.w * b.w;
}

// ---------------------------------------------------------------------------
// tokens f32 -> f16
// ---------------------------------------------------------------------------
__global__ __launch_bounds__(256) void tok_convert(const float* __restrict__ in,
                                                   _Float16* __restrict__ out)
{
    const int n4 = (BSZ * 2048 * 256) / 4;
    for (int i = blockIdx.x * 256 + threadIdx.x; i < n4; i += gridDim.x * 256) {
        float4 v = ((const float4*)in)[i];
        f16x4 h;
        h[0] = (_Float16)v.x; h[1] = (_Float16)v.y;
        h[2] = (_Float16)v.z; h[3] = (_Float16)v.w;
        ((f16x4*)out)[i] = h;
    }
}

// ---------------------------------------------------------------------------
// 64x64 f32->f16 transpose tile through LDS
// ---------------------------------------------------------------------------
__device__ inline void tpose64(const float* __restrict__ src, int Csrc,
                               _Float16* __restrict__ dst, int Rsrc,
                               int r0, int c0, _Float16 (*tbuf)[72], int tid)
{
#pragma unroll
    for (int it = 0; it < 4; it++) {
        int idx = tid + it * 256;
        int rr = idx >> 4, c4 = idx & 15;
        float4 w = *(const float4*)(src + (size_t)(r0 + rr) * Csrc + c0 + c4 * 4);
        tbuf[c4 * 4 + 0][rr] = (_Float16)w.x;
        tbuf[c4 * 4 + 1][rr] = (_Float16)w.y;
        tbuf[c4 * 4 + 2][rr] = (_Float16)w.z;
        tbuf[c4 * 4 + 3][rr] = (_Float16)w.w;
    }
    __syncthreads();
#pragma unroll
    for (int it = 0; it < 2; it++) {
        int idx = tid + it * 256;
        int orr = idx >> 3, oc = idx & 7;
        *(f16x8*)(dst + (size_t)(c0 + orr) * Rsrc + r0 + oc * 8) = *(const f16x8*)&tbuf[orr][oc * 8];
    }
}

// ---------------------------------------------------------------------------
// prep: transposed f16 weights, qn, cls_n, qint2 = q@Wqi + bqi + bqs
// ---------------------------------------------------------------------------
__global__ __launch_bounds__(256) void prep(
    const float* __restrict__ Wk, const float* __restrict__ Wv,
    const float* __restrict__ Wqs, const float* __restrict__ Wf1,
    const float* __restrict__ Wf2,
    const float* __restrict__ intent_q, const float* __restrict__ Wqi,
    const float* __restrict__ bqi, const float* __restrict__ bqs,
    const float* __restrict__ cls_embed,
    _Float16* __restrict__ wkT, _Float16* __restrict__ wvT,
    _Float16* __restrict__ wqsT, _Float16* __restrict__ wf1T,
    _Float16* __restrict__ wf2T,
    float* __restrict__ qint2, float* __restrict__ qn, float* __restrict__ clsn)
{
    __shared__ _Float16 tbuf[64][72];
    __shared__ float buf[256];
    __shared__ float red[4];
    const int t = threadIdx.x, blk = blockIdx.x;
    const int lane = t & 63, w = t >> 6;

    if (blk < 112) {
        if (blk < 16)       tpose64(Wk, 256, wkT, 256, (blk >> 2) * 64, (blk & 3) * 64, tbuf, t);
        else if (blk < 32)  { int tt = blk - 16; tpose64(Wv, 256, wvT, 256, (tt >> 2) * 64, (tt & 3) * 64, tbuf, t); }
        else if (blk < 48)  { int tt = blk - 32; tpose64(Wqs, 256, wqsT, 256, (tt >> 2) * 64, (tt & 3) * 64, tbuf, t); }
        else if (blk < 80)  { int tt = blk - 48; tpose64(Wf1, 512, wf1T, 256, (tt & 3) * 64, (tt >> 2) * 64, tbuf, t); }
        else                { int tt = blk - 80; tpose64(Wf2, 256, wf2T, 512, (tt >> 2) * 64, (tt & 3) * 64, tbuf, t); }
    } else if (blk < 240) {
        int i = blk - 112;
        float x = intent_q[(size_t)i * 256 + t];
        buf[t] = x;
        float ss = x * x;
#pragma unroll
        for (int m = 1; m < 64; m <<= 1) ss += __shfl_xor(ss, m, 64);
        if (lane == 0) red[w] = ss;
        __syncthreads();
        float tot = red[0] + red[1] + red[2] + red[3];
        qn[(size_t)i * 256 + t] = x / fmaxf(sqrtf(tot), 1e-12f);
        float acc = bqi[t] + bqs[t];
        for (int e = 0; e < 256; e += 4) {
            const float4 q4 = *(const float4*)&buf[e];
            acc += q4.x * Wqi[(size_t)(e + 0) * 256 + t];
            acc += q4.y * Wqi[(size_t)(e + 1) * 256 + t];
            acc += q4.z * Wqi[(size_t)(e + 2) * 256 + t];
            acc += q4.w * Wqi[(size_t)(e + 3) * 256 + t];
        }
        qint2[(size_t)i * 256 + t] = acc;
    } else {
        int b = blk - 240;
        float x = cls_embed[(size_t)b * 256 + t];
        float ss = x * x;
#pragma unroll
        for (int m = 1; m < 64; m <<= 1) ss += __shfl_xor(ss, m, 64);
        if (lane == 0) red[w] = ss;
        __syncthreads();
        float tot = red[0] + red[1] + red[2] + red[3];
        clsn[(size_t)b * 256 + t] = x / fmaxf(sqrtf(tot), 1e-12f);
    }
}

// ---------------------------------------------------------------------------
// kv projection (merged): bx<2048 -> k path, else v path. 64 thr.
// k: k16[b][s][d] (m=d via A=wkT); v: vT16[b][d][s] (m=s via A=tok)
// ---------------------------------------------------------------------------
__global__ __launch_bounds__(64) void kv_proj(
    const _Float16* __restrict__ tok,
    const _Float16* __restrict__ wkT, const _Float16* __restrict__ wvT,
    const float* __restrict__ bk, const float* __restrict__ bv,
    _Float16* __restrict__ k16, _Float16* __restrict__ vT16)
{
    const int lane = threadIdx.x, l15 = lane & 15, quad = lane >> 4;
    const int bx = blockIdx.x;
    if (bx < 2048) {
        const int b = bx >> 6, mp = (bx >> 3) & 7, se = bx & 7;
        const _Float16* tb = tok + (size_t)b * 2048 * 256;
        f16x8 a0[8], a1[8];
#pragma unroll
        for (int ks = 0; ks < 8; ks++) {
            a0[ks] = *(const f16x8*)(wkT + (size_t)(mp * 32 + l15) * 256 + ks * 32 + quad * 8);
            a1[ks] = *(const f16x8*)(wkT + (size_t)(mp * 32 + 16 + l15) * 256 + ks * 32 + quad * 8);
        }
        f32x4 bi0 = *(const f32x4*)(bk + mp * 32 + quad * 4);
        f32x4 bi1 = *(const f32x4*)(bk + mp * 32 + 16 + quad * 4);
        for (int nt = 0; nt < 16; nt++) {
            int s = se * 256 + nt * 16 + l15;
            f32x4 c0 = {0.f, 0.f, 0.f, 0.f}, c1 = {0.f, 0.f, 0.f, 0.f};
#pragma unroll
            for (int ks = 0; ks < 8; ks++) {
                f16x8 bf = *(const f16x8*)(tb + (size_t)s * 256 + ks * 32 + quad * 8);
                c0 = MFMA16(a0[ks], bf, c0);
                c1 = MFMA16(a1[ks], bf, c1);
            }
            f16x4 p0, p1;
#pragma unroll
            for (int reg = 0; reg < 4; reg++) {
                p0[reg] = (_Float16)(c0[reg] + bi0[reg]);
                p1[reg] = (_Float16)(c1[reg] + bi1[reg]);
            }
            _Float16* kp = k16 + ((size_t)b * 2048 + s) * 256 + mp * 32 + quad * 4;
            *(f16x4*)kp = p0;
            *(f16x4*)(kp + 16) = p1;
        }
    } else {
        const int bb = bx - 2048;
        const int b = bb >> 6, sp = bb & 63;
        const _Float16* tb = tok + (size_t)b * 2048 * 256;
        f16x8 a0[8], a1[8];
#pragma unroll
        for (int ks = 0; ks < 8; ks++) {
            a0[ks] = *(const f16x8*)(tb + (size_t)(sp * 32 + l15) * 256 + ks * 32 + quad * 8);
            a1[ks] = *(const f16x8*)(tb + (size_t)(sp * 32 + 16 + l15) * 256 + ks * 32 + quad * 8);
        }
        for (int nt = 0; nt < 16; nt++) {
            int d = nt * 16 + l15;
            f32x4 c0 = {0.f, 0.f, 0.f, 0.f}, c1 = {0.f, 0.f, 0.f, 0.f};
#pragma unroll
            for (int ks = 0; ks < 8; ks++) {
                f16x8 bf = *(const f16x8*)(wvT + (size_t)d * 256 + ks * 32 + quad * 8);
                c0 = MFMA16(a0[ks], bf, c0);
                c1 = MFMA16(a1[ks], bf, c1);
            }
            float bbv = bv[d];
            f16x4 p0, p1;
#pragma unroll
            for (int reg = 0; reg < 4; reg++) {
                p0[reg] = (_Float16)(c0[reg] + bbv);
                p1[reg] = (_Float16)(c1[reg] + bbv);
            }
            _Float16* vp = vT16 + ((size_t)b * 256 + d) * 2048 + sp * 32 + quad * 4;
            *(f16x4*)vp = p0;
            *(f16x4*)(vp + 16) = p1;
        }
    }
}

// ---------------------------------------------------------------------------
// slots init
// ---------------------------------------------------------------------------
__global__ __launch_bounds__(256) void slots_init(
    const float* __restrict__ noise, const float* __restrict__ slot_mu,
    const float* __restrict__ slot_sigma, float* __restrict__ slots)
{
    int e4 = blockIdx.x * 256 + threadIdx.x;
    int d4 = e4 & 63;
    int r  = (e4 >> 6) & 511;
    int b  = e4 >> 15;
    int i = r >> 2, n = r & 3;
    float4 mu = *(const float4*)(slot_mu + n * 256 + d4 * 4);
    float4 sg = *(const float4*)(slot_sigma + n * 256 + d4 * 4);
    float4 ns = *(const float4*)(noise + (((size_t)i * BSZ + b) * 4 + n) * 256 + d4 * 4);
    float4 o;
    o.x = mu.x + ns.x * sg.x; o.y = mu.y + ns.y * sg.y;
    o.z = mu.z + ns.z * sg.z; o.w = mu.w + ns.w * sg.w;
    *(float4*)(slots + (size_t)e4 * 4) = o;
}

// ---------------------------------------------------------------------------
// qslot: qs16 = (slots@Wqs + qint2)/16. grid 1024: rb=bx>>2, dq=bx&3 (4 dt)
// ---------------------------------------------------------------------------
__global__ __launch_bounds__(256) void qslot_k(
    const float* __restrict__ slots, const _Float16* __restrict__ wqsT,
    const float* __restrict__ qint2, _Float16* __restrict__ qs16)
{
    const int tid = threadIdx.x, lane = tid & 63, wv = tid >> 6;
    const int l15 = lane & 15, quad = lane >> 4;
    const int bx = blockIdx.x, rb = bx >> 2, dq = bx & 3;
    const int gr = rb * 64 + wv * 16 + l15;

    f16x8 bs[8];
    const float* sp = slots + (size_t)gr * 256 + quad * 8;
#pragma unroll
    for (int ks = 0; ks < 8; ks++) {
        float4 a = *(const float4*)(sp + ks * 32);
        float4 b = *(const float4*)(sp + ks * 32 + 4);
        f16x8 h;
        h[0] = (_Float16)a.x; h[1] = (_Float16)a.y; h[2] = (_Float16)a.z; h[3] = (_Float16)a.w;
        h[4] = (_Float16)b.x; h[5] = (_Float16)b.y; h[6] = (_Float16)b.z; h[7] = (_Float16)b.w;
        bs[ks] = h;
    }
    const int iq = (gr & 511) >> 2;
#pragma unroll
    for (int dt = 0; dt < 4; dt++) {
        int dti = dq * 4 + dt;
        f32x4 c = {0.f, 0.f, 0.f, 0.f};
#pragma unroll
        for (int ks = 0; ks < 8; ks++)
            c = MFMA16(*(const f16x8*)(wqsT + (size_t)(dti * 16 + l15) * 256 + ks * 32 + quad * 8), bs[ks], c);
        int d0 = dti * 16 + quad * 4;
        float4 qi = *(const float4*)(qint2 + (size_t)iq * 256 + d0);
        f16x4 o;
#pragma unroll
        for (int reg = 0; reg < 4; reg++) o[reg] = (_Float16)((c[reg] + qi[reg]) * 0.0625f);
        *(f16x4*)(qs16 + (size_t)gr * 256 + d0) = o;
    }
}

// ---------------------------------------------------------------------------
// attn_k: fused logits+exp+rowsum+PV, barrier-free (per-wave LDS only).
// grid 1024: b = bx&31, rb = (bx>>5)&7, sk = bx>>8 (s-chunk of 512).
// Wave = 16 rows x full 256 d. Per 64-s sub-chunk: logits (4 st x 8 kf MFMA)
// -> exp -> P to per-wave LDS -> PV (16 dt x 2 kf MFMA into O-acc).
// Outputs: Opart[sk][row][256] f16, psum4[sk][row] f32.
// ---------------------------------------------------------------------------
__global__ __launch_bounds__(256) void attn_k(
    const _Float16* __restrict__ qs16, const _Float16* __restrict__ k16,
    const _Float16* __restrict__ vT16,
    _Float16* __restrict__ Opart, float* __restrict__ psum4)
{
    __shared__ __align__(16) _Float16 arena[4 * 4224];   // per-wave 8448 B

    const int tid = threadIdx.x, lane = tid & 63, wv = tid >> 6;
    const int l15 = lane & 15, quad = lane >> 4;
    const int bx = blockIdx.x;
    const int b = bx & 31, rb = (bx >> 5) & 7, sk = bx >> 8;
    const int gr0 = b * 512 + rb * 64 + wv * 16;
    const int s0k = sk * 512;

    _Float16* wlds = arena + wv * 4224;   // P: 16x72 (stride 72); O-tp: 16x264

    // hoist q X-frags
    f16x8 q[8];
#pragma unroll
    for (int kf = 0; kf < 8; kf++)
        q[kf] = *(const f16x8*)(qs16 + (size_t)(gr0 + l15) * 256 + kf * 32 + quad * 8);

    const _Float16* kB = k16 + ((size_t)b * 2048 + s0k + l15) * 256 + quad * 8;
    const _Float16* vB = vT16 + ((size_t)b * 256 + l15) * 2048 + s0k + quad * 8;

    f32x4 O[16];
#pragma unroll
    for (int dt = 0; dt < 16; dt++) O[dt] = (f32x4){0.f, 0.f, 0.f, 0.f};
    float ps[4] = {0.f, 0.f, 0.f, 0.f};

    for (int sub = 0; sub < 8; sub++) {
        const int ss = sub * 64;
        // ---- logits: 4 s-tiles of 16
#pragma unroll
        for (int st = 0; st < 4; st++) {
            f32x4 c = {0.f, 0.f, 0.f, 0.f};
#pragma unroll
            for (int kf = 0; kf < 8; kf++)
                c = MFMA16(q[kf], *(const f16x8*)(kB + (size_t)(ss + st * 16) * 256 + kf * 32), c);
#pragma unroll
            for (int reg = 0; reg < 4; reg++) {
                float p = __expf(fminf(c[reg], 10.5f));
                ps[reg] += p;
                wlds[(quad * 4 + reg) * 72 + st * 16 + l15] = (_Float16)p;
            }
        }
        // ---- PV over this 64-s sub-chunk
        f16x8 xp[2];
#pragma unroll
        for (int kf = 0; kf < 2; kf++)
            xp[kf] = *(const f16x8*)(wlds + l15 * 72 + kf * 32 + quad * 8);
#pragma unroll
        for (int dt = 0; dt < 16; dt++) {
            const _Float16* vp = vB + (size_t)(dt * 16) * 2048 + ss;
            O[dt] = MFMA16(xp[0], *(const f16x8*)(vp), O[dt]);
            O[dt] = MFMA16(xp[1], *(const f16x8*)(vp + 32), O[dt]);
        }
    }

    // ---- row sums (reduce over l15 lanes) -> psum4
#pragma unroll
    for (int msk = 1; msk <= 8; msk <<= 1)
#pragma unroll
        for (int reg = 0; reg < 4; reg++) ps[reg] += __shfl_xor(ps[reg], msk, 64);
    if (l15 == 0) {
#pragma unroll
        for (int reg = 0; reg < 4; reg++)
            psum4[(size_t)sk * 16384 + gr0 + quad * 4 + reg] = ps[reg];
    }

    // ---- O transpose via per-wave LDS (f16), coalesced store
#pragma unroll
    for (int dt = 0; dt < 16; dt++)
#pragma unroll
        for (int reg = 0; reg < 4; reg++)
            wlds[(quad * 4 + reg) * 264 + dt * 16 + l15] = (_Float16)O[dt][reg];
#pragma unroll
    for (int j = 0; j < 8; j++) {
        int u = lane + j * 64;
        int row = u >> 5, col8 = u & 31;
        *(f16x8*)(Opart + ((size_t)sk * 16384 + gr0 + row) * 256 + col8 * 8) =
            *(const f16x8*)(wlds + row * 264 + col8 * 8);
    }
}

// ---------------------------------------------------------------------------
// LN: y = slots + (sum Opart)/(sum psum); x1 = LN1 -> slots; h16 = LN2(x1).
// ---------------------------------------------------------------------------
__global__ __launch_bounds__(256) void ln_k(
    const _Float16* __restrict__ Opart, const float* __restrict__ psum4,
    float* __restrict__ slots, _Float16* __restrict__ h16,
    const float* __restrict__ ln1_g, const float* __restrict__ ln1_b,
    const float* __restrict__ ln2_g, const float* __restrict__ ln2_b)
{
    const int tid = threadIdx.x, lane = tid & 63, wv = tid >> 6;
    const int row = blockIdx.x * 4 + wv;
    float l = 0.f;
#pragma unroll
    for (int j = 0; j < 4; j++) l += psum4[(size_t)j * 16384 + row];
    float invl = 1.f / l;
    float4 o4 = {0.f, 0.f, 0.f, 0.f};
#pragma unroll
    for (int j = 0; j < 4; j++) {
        f16x4 p = *(const f16x4*)(Opart + ((size_t)j * 16384 + row) * 256 + lane * 4);
        o4.x += (float)p[0]; o4.y += (float)p[1]; o4.z += (float)p[2]; o4.w += (float)p[3];
    }
    float4 s4 = *(const float4*)(slots + (size_t)row * 256 + lane * 4);
    float4 y;
    y.x = s4.x + o4.x * invl; y.y = s4.y + o4.y * invl;
    y.z = s4.z + o4.z * invl; y.w = s4.w + o4.w * invl;

    float sm = y.x + y.y + y.z + y.w, sq = dot4f(y, y);
#pragma unroll
    for (int m = 1; m < 64; m <<= 1) { sm += __shfl_xor(sm, m, 64); sq += __shfl_xor(sq, m, 64); }
    float mean = sm * (1.f / 256.f);
    float rstd = rsqrtf(sq * (1.f / 256.f) - mean * mean + 1e-5f);
    float4 g1 = *(const float4*)(ln1_g + lane * 4);
    float4 b1 = *(const float4*)(ln1_b + lane * 4);
    float4 x1;
    x1.x = (y.x - mean) * rstd * g1.x + b1.x;
    x1.y = (y.y - mean) * rstd * g1.y + b1.y;
    x1.z = (y.z - mean) * rstd * g1.z + b1.z;
    x1.w = (y.w - mean) * rstd * g1.w + b1.w;
    *(float4*)(slots + (size_t)row * 256 + lane * 4) = x1;

    float sm2 = x1.x + x1.y + x1.z + x1.w, sq2 = dot4f(x1, x1);
#pragma unroll
    for (int m = 1; m < 64; m <<= 1) { sm2 += __shfl_xor(sm2, m, 64); sq2 += __shfl_xor(sq2, m, 64); }
    float mean2 = sm2 * (1.f / 256.f);
    float rstd2 = rsqrtf(sq2 * (1.f / 256.f) - mean2 * mean2 + 1e-5f);
    float4 g2 = *(const float4*)(ln2_g + lane * 4);
    float4 b2 = *(const float4*)(ln2_b + lane * 4);
    f16x4 h;
    h[0] = (_Float16)((x1.x - mean2) * rstd2 * g2.x + b2.x);
    h[1] = (_Float16)((x1.y - mean2) * rstd2 * g2.y + b2.y);
    h[2] = (_Float16)((x1.z - mean2) * rstd2 * g2.z + b2.z);
    h[3] = (_Float16)((x1.w - mean2) * rstd2 * g2.w + b2.w);
    *(f16x4*)(h16 + (size_t)row * 256 + lane * 4) = h;
}

// ---------------------------------------------------------------------------
// FFN1: act16 = gelu(h16 @ Wf1 + bf1). grid 1024: rb=bx>>2, hq=bx&3 (8 ht)
// ---------------------------------------------------------------------------
__global__ __launch_bounds__(256) void ffn1_k(
    const _Float16* __restrict__ h16, const _Float16* __restrict__ wf1T,
    const float* __restrict__ bf1, _Float16* __restrict__ act16)
{
    const int tid = threadIdx.x, lane = tid & 63, wv = tid >> 6;
    const int l15 = lane & 15, quad = lane >> 4;
    const int bx = blockIdx.x, rb = bx >> 2, hq = bx & 3;
    const int gr = rb * 64 + wv * 16 + l15;

    f16x8 bh[8];
#pragma unroll
    for (int ks = 0; ks < 8; ks++)
        bh[ks] = *(const f16x8*)(h16 + (size_t)gr * 256 + ks * 32 + quad * 8);
#pragma unroll 2
    for (int ht = 0; ht < 8; ht++) {
        int hti = hq * 8 + ht;
        f32x4 c = {0.f, 0.f, 0.f, 0.f};
#pragma unroll
        for (int ks = 0; ks < 8; ks++)
            c = MFMA16(*(const f16x8*)(wf1T + (size_t)(hti * 16 + l15) * 256 + ks * 32 + quad * 8), bh[ks], c);
        int hc0 = hti * 16 + quad * 4;
        float4 bb = *(const float4*)(bf1 + hc0);
        f16x4 o;
#pragma unroll
        for (int reg = 0; reg < 4; reg++) {
            float xg = c[reg] + bb[reg];
            o[reg] = (_Float16)(0.5f * xg * (1.f + erff(xg * 0.70710678118654752f)));
        }
        *(f16x4*)(act16 + (size_t)gr * 512 + hc0) = o;
    }
}

// ---------------------------------------------------------------------------
// FFN2: slots = x1 + act16 @ Wf2 + bf2. grid 1024: rb=bx>>2, dq=bx&3 (4 dt)
// ---------------------------------------------------------------------------
__global__ __launch_bounds__(256) void ffn2_k(
    const _Float16* __restrict__ act16, const _Float16* __restrict__ wf2T,
    const float* __restrict__ bf2, float* __restrict__ slots)
{
    const int tid = threadIdx.x, lane = tid & 63, wv = tid >> 6;
    const int l15 = lane & 15, quad = lane >> 4;
    const int bx = blockIdx.x, rb = bx >> 2, dq = bx & 3;
    const int gr = rb * 64 + wv * 16 + l15;

    f32x4 c[4];
#pragma unroll
    for (int dt = 0; dt < 4; dt++) {
        int d0 = (dq * 4 + dt) * 16 + quad * 4;
        float4 x4 = *(const float4*)(slots + (size_t)gr * 256 + d0);
        float4 bb = *(const float4*)(bf2 + d0);
        c[dt] = (f32x4){x4.x + bb.x, x4.y + bb.y, x4.z + bb.z, x4.w + bb.w};
    }
    const _Float16* ap = act16 + (size_t)gr * 512 + quad * 8;
    for (int ks = 0; ks < 16; ks++) {
        f16x8 bfrag = *(const f16x8*)(ap + ks * 32);
#pragma unroll
        for (int dt = 0; dt < 4; dt++)
            c[dt] = MFMA16(*(const f16x8*)(wf2T + (size_t)((dq * 4 + dt) * 16 + l15) * 512 + ks * 32 + quad * 8), bfrag, c[dt]);
    }
#pragma unroll
    for (int dt = 0; dt < 4; dt++)
        *(f32x4*)(slots + (size_t)gr * 256 + (dq * 4 + dt) * 16 + quad * 4) = c[dt];
}

// ---------------------------------------------------------------------------
// final scoring: wave per (b, i)
// ---------------------------------------------------------------------------
__global__ __launch_bounds__(256) void final_k(
    const float* __restrict__ slots, const float* __restrict__ qn,
    const float* __restrict__ clsn,
    const float* __restrict__ alphap, const float* __restrict__ tempp,
    float* __restrict__ out)
{
    const int tid = threadIdx.x, lane = tid & 63, wv = tid >> 6;
    const int bx = blockIdx.x;
    const int b = bx & 31, ig = bx >> 5;
    const int i = ig * 4 + wv;

    float4 qv = *(const float4*)(qn + (size_t)i * 256 + lane * 4);
    float4 xs[4];
    float st4[4];
#pragma unroll
    for (int n = 0; n < 4; n++) {
        xs[n] = *(const float4*)(slots + ((size_t)b * 512 + i * 4 + n) * 256 + lane * 4);
        float ss = dot4f(xs[n], xs[n]);
        float sq = dot4f(xs[n], qv);
#pragma unroll
        for (int m = 1; m < 64; m <<= 1) { ss += __shfl_xor(ss, m, 64); sq += __shfl_xor(sq, m, 64); }
        st4[n] = sq / fmaxf(sqrtf(ss), 1e-12f);
    }
    float mx = fmaxf(fmaxf(st4[0], st4[1]), fmaxf(st4[2], st4[3]));
    float e0 = __expf(st4[0] - mx), e1 = __expf(st4[1] - mx);
    float e2 = __expf(st4[2] - mx), e3 = __expf(st4[3] - mx);
    float inv = 1.f / (e0 + e1 + e2 + e3);
    float4 smv;
    smv.x = (e0 * xs[0].x + e1 * xs[1].x + e2 * xs[2].x + e3 * xs[3].x) * inv;
    smv.y = (e0 * xs[0].y + e1 * xs[1].y + e2 * xs[2].y + e3 * xs[3].y) * inv;
    smv.z = (e0 * xs[0].z + e1 * xs[1].z + e2 * xs[2].z + e3 * xs[3].z) * inv;
    smv.w = (e0 * xs[0].w + e1 * xs[1].w + e2 * xs[2].w + e3 * xs[3].w) * inv;
    float ssm = dot4f(smv, smv);
    float sqn = dot4f(smv, qv);
    float4 cv = *(const float4*)(clsn + (size_t)b * 256 + lane * 4);
    float cq = dot4f(cv, qv);
#pragma unroll
    for (int m = 1; m < 64; m <<= 1) {
        ssm += __shfl_xor(ssm, m, 64);
        sqn += __shfl_xor(sqn, m, 64);
        cq  += __shfl_xor(cq,  m, 64);
    }
    if (lane == 0) {
        float score = cq + alphap[0] * sqn / fmaxf(sqrtf(ssm), 1e-12f);
        out[(size_t)b * NI + i] = score / fmaxf(tempp[0], 1e-4f);
    }
}

// ---------------------------------------------------------------------------
extern "C" void kernel_launch(void* const* d_in, const int* in_sizes, int n_in,
                              void* d_out, int out_size, void* d_ws, size_t ws_size,
                              hipStream_t stream)
{
    const float* tokens     = (const float*)d_in[0];
    const float* cls_embed  = (const float*)d_in[1];
    const float* intent_q   = (const float*)d_in[2];
    const float* noise      = (const float*)d_in[3];
    const float* Wk  = (const float*)d_in[4];
    const float* bk  = (const float*)d_in[5];
    const float* Wv  = (const float*)d_in[6];
    const float* bv  = (const float*)d_in[7];
    const float* Wqs = (const float*)d_in[8];
    const float* bqs = (const float*)d_in[9];
    const float* Wqi = (const float*)d_in[10];
    const float* bqi = (const float*)d_in[11];
    const float* ln1g = (const float*)d_in[12];
    const float* ln1b = (const float*)d_in[13];
    const float* ln2g = (const float*)d_in[14];
    const float* ln2b = (const float*)d_in[15];
    const float* Wf1 = (const float*)d_in[16];
    const float* bf1 = (const float*)d_in[17];
    const float* Wf2 = (const float*)d_in[18];
    const float* bf2 = (const float*)d_in[19];
    const float* slot_mu    = (const float*)d_in[20];
    const float* slot_sigma = (const float*)d_in[21];
    const float* alphap = (const float*)d_in[22];
    const float* tempp  = (const float*)d_in[23];
    float* out = (float*)d_out;

    char* base = (char*)d_ws;
    // region A (33.5 MB): tok16 during projection; later qs16 | (free) | h16
    _Float16* tok16 = (_Float16*)(base);
    _Float16* qs16  = (_Float16*)(base);                        //  8388608 B
    _Float16* h16   = (_Float16*)(base + 25165824u);            //  8388608 B
    _Float16* k16   = (_Float16*)(base + 33554432u);            // 33554432 B
    _Float16* vT16  = (_Float16*)(base + 67108864u);            // 33554432 B
    _Float16* Opart = (_Float16*)(base + 100663296u);           // 33554432 B (aliases act16)
    _Float16* act16 = (_Float16*)(base + 100663296u);           // 16777216 B
    float* slots    = (float*)(base + 134217728u);              // 16777216 B
    _Float16* wkT   = (_Float16*)(base + 150994944u);           //   131072 B
    _Float16* wvT   = (_Float16*)(base + 151126016u);
    _Float16* wqsT  = (_Float16*)(base + 151257088u);
    _Float16* wf1T  = (_Float16*)(base + 151388160u);           //   262144 B
    _Float16* wf2T  = (_Float16*)(base + 151650304u);           //   262144 B
    float* qint2    = (float*)(base + 151912448u);              //   131072 B
    float* qnb      = (float*)(base + 152043520u);              //   131072 B
    float* clsn     = (float*)(base + 152174592u);              //    32768 B
    float* psum4    = (float*)(base + 152207360u);              //   262144 B

    tok_convert<<<2048, 256, 0, stream>>>(tokens, tok16);
    prep<<<272, 256, 0, stream>>>(Wk, Wv, Wqs, Wf1, Wf2, intent_q, Wqi, bqi, bqs,
                                  cls_embed, wkT, wvT, wqsT, wf1T, wf2T,
                                  qint2, qnb, clsn);
    kv_proj<<<4096, 64, 0, stream>>>(tok16, wkT, wvT, bk, bv, k16, vT16);
    slots_init<<<4096, 256, 0, stream>>>(noise, slot_mu, slot_sigma, slots);

    for (int it = 0; it < 3; it++) {
        qslot_k<<<1024, 256, 0, stream>>>(slots, wqsT, qint2, qs16);
        attn_k<<<1024, 256, 0, stream>>>(qs16, k16, vT16, Opart, psum4);
        ln_k<<<4096, 256, 0, stream>>>(Opart, psum4, slots, h16, ln1g, ln1b, ln2g, ln2b);
        ffn1_k<<<1024, 256, 0, stream>>>(h16, wf1T, bf1, act16);
        ffn2_k<<<1024, 256, 0, stream>>>(act16, wf2T, bf2, slots);
    }
    final_k<<<1024, 256, 0, stream>>>(slots, qnb, clsn, alphap, tempp, out);
}

// Round 6
// 1230.259 us; speedup vs baseline: 1.1873x; 1.1625x over previous
//
#include <hip/hip_runtime.h>
#include <math.h>

#define BSZ 32
#define NI  128

typedef __attribute__((ext_vector_type(8))) _Float16 f16x8;
typedef __attribute__((ext_vector_type(4))) _Float16 f16x4;
typedef __attribute__((ext_vector_type(4))) float    f32x4;

// MFMA16(X, Y, C): C[row = quad*4+reg <- X's l15][col = l15 <- Y's l15]
// X,Y k-index = quad*8 + j.
// Tiled operand format: 1KB tiles [(r>>4)][(k>>5)], inner
//   ((r&15)*4 + ((k>>3)&3))*8 + (k&7)  == l15*32 + quad*8 + j for a fragment.
#define MFMA16(a, b, c) __builtin_amdgcn_mfma_f32_16x16x32_f16((a), (b), (c), 0, 0, 0)

__device__ inline float dot4f(float4 a, float4 b) {
    return a.x * b.x + a.y * b.y + a.z * b.z + a.w * b.w;
}

// ---------------------------------------------------------------------------
// tokens f32 -> f16 TILED. thread -> (row sg, 8-d group d8)
// ---------------------------------------------------------------------------
__global__ __launch_bounds__(256) void tok_convert(const float* __restrict__ in,
                                                   _Float16* __restrict__ tokT)
{
    int idx = blockIdx.x * 256 + threadIdx.x;       // 2M threads
    int sg = idx >> 5, d8 = idx & 31;
    const float* p = in + (size_t)sg * 256 + d8 * 8;
    float4 a = *(const float4*)p, b = *(const float4*)(p + 4);
    f16x8 h;
    h[0] = (_Float16)a.x; h[1] = (_Float16)a.y; h[2] = (_Float16)a.z; h[3] = (_Float16)a.w;
    h[4] = (_Float16)b.x; h[5] = (_Float16)b.y; h[6] = (_Float16)b.z; h[7] = (_Float16)b.w;
    *(f16x8*)(tokT + ((size_t)(sg >> 4) * 8 + (d8 >> 2)) * 512 + (sg & 15) * 32 + (d8 & 3) * 8) = h;
}

// ---------------------------------------------------------------------------
// 64x64 f32->f16 transpose tile -> TILED output (element (n,k) from src[k][n])
// ---------------------------------------------------------------------------
__device__ inline void tpose64(const float* __restrict__ src, int Csrc,
                               _Float16* __restrict__ dstT, int KT,
                               int r0, int c0, _Float16 (*tbuf)[72], int tid)
{
#pragma unroll
    for (int it = 0; it < 4; it++) {
        int idx = tid + it * 256;
        int rr = idx >> 4, c4 = idx & 15;
        float4 w = *(const float4*)(src + (size_t)(r0 + rr) * Csrc + c0 + c4 * 4);
        tbuf[c4 * 4 + 0][rr] = (_Float16)w.x;
        tbuf[c4 * 4 + 1][rr] = (_Float16)w.y;
        tbuf[c4 * 4 + 2][rr] = (_Float16)w.z;
        tbuf[c4 * 4 + 3][rr] = (_Float16)w.w;
    }
    __syncthreads();
#pragma unroll
    for (int it = 0; it < 2; it++) {
        int idx = tid + it * 256;
        int orr = idx >> 3, oc8 = idx & 7;
        int n = c0 + orr;
        size_t tile = (size_t)(n >> 4) * KT + (r0 >> 5) + (oc8 >> 2);
        *(f16x8*)(dstT + tile * 512 + (n & 15) * 32 + (oc8 & 3) * 8) = *(const f16x8*)&tbuf[orr][oc8 * 8];
    }
}

// ---------------------------------------------------------------------------
// prep: tiled f16 weights, qn, cls_n, qint2 = q@Wqi + bqi + bqs
// ---------------------------------------------------------------------------
__global__ __launch_bounds__(256) void prep(
    const float* __restrict__ Wk, const float* __restrict__ Wv,
    const float* __restrict__ Wqs, const float* __restrict__ Wf1,
    const float* __restrict__ Wf2,
    const float* __restrict__ intent_q, const float* __restrict__ Wqi,
    const float* __restrict__ bqi, const float* __restrict__ bqs,
    const float* __restrict__ cls_embed,
    _Float16* __restrict__ wkT, _Float16* __restrict__ wvT,
    _Float16* __restrict__ wqsT, _Float16* __restrict__ wf1T,
    _Float16* __restrict__ wf2T,
    float* __restrict__ qint2, float* __restrict__ qn, float* __restrict__ clsn)
{
    __shared__ _Float16 tbuf[64][72];
    __shared__ float buf[256];
    __shared__ float red[4];
    const int t = threadIdx.x, blk = blockIdx.x;
    const int lane = t & 63, w = t >> 6;

    if (blk < 112) {
        if (blk < 16)       tpose64(Wk, 256, wkT, 8, (blk >> 2) * 64, (blk & 3) * 64, tbuf, t);
        else if (blk < 32)  { int tt = blk - 16; tpose64(Wv, 256, wvT, 8, (tt >> 2) * 64, (tt & 3) * 64, tbuf, t); }
        else if (blk < 48)  { int tt = blk - 32; tpose64(Wqs, 256, wqsT, 8, (tt >> 2) * 64, (tt & 3) * 64, tbuf, t); }
        else if (blk < 80)  { int tt = blk - 48; tpose64(Wf1, 512, wf1T, 8, (tt & 3) * 64, (tt >> 2) * 64, tbuf, t); }
        else                { int tt = blk - 80; tpose64(Wf2, 256, wf2T, 16, (tt >> 2) * 64, (tt & 3) * 64, tbuf, t); }
    } else if (blk < 240) {
        int i = blk - 112;
        float x = intent_q[(size_t)i * 256 + t];
        buf[t] = x;
        float ss = x * x;
#pragma unroll
        for (int m = 1; m < 64; m <<= 1) ss += __shfl_xor(ss, m, 64);
        if (lane == 0) red[w] = ss;
        __syncthreads();
        float tot = red[0] + red[1] + red[2] + red[3];
        qn[(size_t)i * 256 + t] = x / fmaxf(sqrtf(tot), 1e-12f);
        float acc = bqi[t] + bqs[t];
        for (int e = 0; e < 256; e += 4) {
            const float4 q4 = *(const float4*)&buf[e];
            acc += q4.x * Wqi[(size_t)(e + 0) * 256 + t];
            acc += q4.y * Wqi[(size_t)(e + 1) * 256 + t];
            acc += q4.z * Wqi[(size_t)(e + 2) * 256 + t];
            acc += q4.w * Wqi[(size_t)(e + 3) * 256 + t];
        }
        qint2[(size_t)i * 256 + t] = acc;
    } else {
        int b = blk - 240;
        float x = cls_embed[(size_t)b * 256 + t];
        float ss = x * x;
#pragma unroll
        for (int m = 1; m < 64; m <<= 1) ss += __shfl_xor(ss, m, 64);
        if (lane == 0) red[w] = ss;
        __syncthreads();
        float tot = red[0] + red[1] + red[2] + red[3];
        clsn[(size_t)b * 256 + t] = x / fmaxf(sqrtf(tot), 1e-12f);
    }
}

// ---------------------------------------------------------------------------
// kv projection. All operands tiled. bx<2048 -> k path, else v path.
// k tiles: [(b*128 + s>>4)*8 + d>>5]; v tiles: [(b*16 + d>>4)*64 + s>>5]
// ---------------------------------------------------------------------------
__global__ __launch_bounds__(64) void kv_proj(
    const _Float16* __restrict__ tokT,
    const _Float16* __restrict__ wkT, const _Float16* __restrict__ wvT,
    const float* __restrict__ bk, const float* __restrict__ bv,
    _Float16* __restrict__ kT, _Float16* __restrict__ vT)
{
    const int lane = threadIdx.x, l15 = lane & 15, quad = lane >> 4;
    const int lofs = l15 * 32 + quad * 8;
    const int bx = blockIdx.x;
    if (bx < 2048) {
        const int b = bx >> 6, mp = (bx >> 3) & 7, se = bx & 7;
        f16x8 a0[8], a1[8];
#pragma unroll
        for (int ks = 0; ks < 8; ks++) {
            a0[ks] = *(const f16x8*)(wkT + ((size_t)(mp * 2) * 8 + ks) * 512 + lofs);
            a1[ks] = *(const f16x8*)(wkT + ((size_t)(mp * 2 + 1) * 8 + ks) * 512 + lofs);
        }
        f32x4 bi0 = *(const f32x4*)(bk + mp * 32 + quad * 4);
        f32x4 bi1 = *(const f32x4*)(bk + mp * 32 + 16 + quad * 4);
        for (int nt = 0; nt < 16; nt++) {
            int stg = se * 16 + nt;
            f32x4 c0 = {0.f, 0.f, 0.f, 0.f}, c1 = {0.f, 0.f, 0.f, 0.f};
#pragma unroll
            for (int ks = 0; ks < 8; ks++) {
                f16x8 bf = *(const f16x8*)(tokT + ((size_t)(b * 128 + stg) * 8 + ks) * 512 + lofs);
                c0 = MFMA16(a0[ks], bf, c0);
                c1 = MFMA16(a1[ks], bf, c1);
            }
            f16x4 p0, p1;
#pragma unroll
            for (int reg = 0; reg < 4; reg++) {
                p0[reg] = (_Float16)(c0[reg] + bi0[reg]);
                p1[reg] = (_Float16)(c1[reg] + bi1[reg]);
            }
            _Float16* tp = kT + ((size_t)(b * 128 + stg) * 8 + mp) * 512 + l15 * 32;
            *(f16x4*)(tp + (quad >> 1) * 8 + (quad & 1) * 4) = p0;
            *(f16x4*)(tp + (2 + (quad >> 1)) * 8 + (quad & 1) * 4) = p1;
        }
    } else {
        const int bb = bx - 2048;
        const int b = bb >> 6, sp = bb & 63;
        f16x8 a0[8], a1[8];
#pragma unroll
        for (int ks = 0; ks < 8; ks++) {
            a0[ks] = *(const f16x8*)(tokT + ((size_t)(b * 128 + sp * 2) * 8 + ks) * 512 + lofs);
            a1[ks] = *(const f16x8*)(tokT + ((size_t)(b * 128 + sp * 2 + 1) * 8 + ks) * 512 + lofs);
        }
        for (int nt = 0; nt < 16; nt++) {
            f32x4 c0 = {0.f, 0.f, 0.f, 0.f}, c1 = {0.f, 0.f, 0.f, 0.f};
#pragma unroll
            for (int ks = 0; ks < 8; ks++) {
                f16x8 bf = *(const f16x8*)(wvT + ((size_t)nt * 8 + ks) * 512 + lofs);
                c0 = MFMA16(a0[ks], bf, c0);
                c1 = MFMA16(a1[ks], bf, c1);
            }
            float bbv = bv[nt * 16 + l15];
            f16x4 p0, p1;
#pragma unroll
            for (int reg = 0; reg < 4; reg++) {
                p0[reg] = (_Float16)(c0[reg] + bbv);
                p1[reg] = (_Float16)(c1[reg] + bbv);
            }
            _Float16* tp = vT + ((size_t)(b * 16 + nt) * 64 + sp) * 512 + l15 * 32;
            *(f16x4*)(tp + (quad >> 1) * 8 + (quad & 1) * 4) = p0;
            *(f16x4*)(tp + (2 + (quad >> 1)) * 8 + (quad & 1) * 4) = p1;
        }
    }
}

// ---------------------------------------------------------------------------
// slots init: writes slots f32 row-major AND slots16 tiled
// ---------------------------------------------------------------------------
__global__ __launch_bounds__(256) void slots_init(
    const float* __restrict__ noise, const float* __restrict__ slot_mu,
    const float* __restrict__ slot_sigma, float* __restrict__ slots,
    _Float16* __restrict__ slotsT)
{
    int idx = blockIdx.x * 256 + threadIdx.x;    // 524288
    int row = idx >> 5, d8 = idx & 31;
    int b = row >> 9, i = (row >> 2) & 127, n = row & 3;
    int d = d8 * 8;
    const float* mp = slot_mu + n * 256 + d;
    const float* sp = slot_sigma + n * 256 + d;
    const float* np = noise + (((size_t)i * BSZ + b) * 4 + n) * 256 + d;
    float4 o0, o1;
    {
        float4 mu = *(const float4*)mp, sg = *(const float4*)sp, ns = *(const float4*)np;
        o0.x = mu.x + ns.x * sg.x; o0.y = mu.y + ns.y * sg.y;
        o0.z = mu.z + ns.z * sg.z; o0.w = mu.w + ns.w * sg.w;
    }
    {
        float4 mu = *(const float4*)(mp + 4), sg = *(const float4*)(sp + 4), ns = *(const float4*)(np + 4);
        o1.x = mu.x + ns.x * sg.x; o1.y = mu.y + ns.y * sg.y;
        o1.z = mu.z + ns.z * sg.z; o1.w = mu.w + ns.w * sg.w;
    }
    *(float4*)(slots + (size_t)row * 256 + d) = o0;
    *(float4*)(slots + (size_t)row * 256 + d + 4) = o1;
    f16x8 h;
    h[0] = (_Float16)o0.x; h[1] = (_Float16)o0.y; h[2] = (_Float16)o0.z; h[3] = (_Float16)o0.w;
    h[4] = (_Float16)o1.x; h[5] = (_Float16)o1.y; h[6] = (_Float16)o1.z; h[7] = (_Float16)o1.w;
    *(f16x8*)(slotsT + ((size_t)(row >> 4) * 8 + (d8 >> 2)) * 512 + (row & 15) * 32 + (d8 & 3) * 8) = h;
}

// ---------------------------------------------------------------------------
// qslot: qsT = (slots@Wqs + qint2)/16, tiled. grid 1024: rb=bx>>2, dq=bx&3
// ---------------------------------------------------------------------------
__global__ __launch_bounds__(256) void qslot_k(
    const _Float16* __restrict__ slotsT, const _Float16* __restrict__ wqsT,
    const float* __restrict__ qint2, _Float16* __restrict__ qsT)
{
    const int tid = threadIdx.x, lane = tid & 63, wv = tid >> 6;
    const int l15 = lane & 15, quad = lane >> 4;
    const int lofs = l15 * 32 + quad * 8;
    const int bx = blockIdx.x, rb = bx >> 2, dq = bx & 3;
    const int rt = rb * 4 + wv;
    const int gr0 = rt * 16;

    f16x8 bs[8];
#pragma unroll
    for (int ks = 0; ks < 8; ks++)
        bs[ks] = *(const f16x8*)(slotsT + ((size_t)rt * 8 + ks) * 512 + lofs);
    const int iq = ((gr0 + l15) & 511) >> 2;
#pragma unroll
    for (int dt = 0; dt < 4; dt++) {
        int dti = dq * 4 + dt;
        f32x4 c = {0.f, 0.f, 0.f, 0.f};
#pragma unroll
        for (int ks = 0; ks < 8; ks++)
            c = MFMA16(*(const f16x8*)(wqsT + ((size_t)dti * 8 + ks) * 512 + lofs), bs[ks], c);
        float4 qi = *(const float4*)(qint2 + (size_t)iq * 256 + dti * 16 + quad * 4);
        f16x4 o;
#pragma unroll
        for (int reg = 0; reg < 4; reg++) o[reg] = (_Float16)((c[reg] + qi[reg]) * 0.0625f);
        *(f16x4*)(qsT + ((size_t)rt * 8 + (dti >> 1)) * 512 + l15 * 32
                  + ((dti & 1) * 2 + (quad >> 1)) * 8 + (quad & 1) * 4) = o;
    }
}

// ---------------------------------------------------------------------------
// attn_k: fused logits+exp+rowsum+PV, barrier-free, all operands tiled.
// grid 1024: b=bx&31, rb=(bx>>5)&7, sk=bx>>8 (512-s chunk)
// ---------------------------------------------------------------------------
__global__ __launch_bounds__(256) void attn_k(
    const _Float16* __restrict__ qsT, const _Float16* __restrict__ kT,
    const _Float16* __restrict__ vT,
    _Float16* __restrict__ Opart, float* __restrict__ psum4)
{
    __shared__ __align__(16) _Float16 arena[4 * 4224];

    const int tid = threadIdx.x, lane = tid & 63, wv = tid >> 6;
    const int l15 = lane & 15, quad = lane >> 4;
    const int lofs = l15 * 32 + quad * 8;
    const int bx = blockIdx.x;
    const int b = bx & 31, rb = (bx >> 5) & 7, sk = bx >> 8;
    const int gr0 = b * 512 + rb * 64 + wv * 16;
    const int rt_q = b * 32 + rb * 4 + wv;

    _Float16* wlds = arena + wv * 4224;

    f16x8 q[8];
#pragma unroll
    for (int kf = 0; kf < 8; kf++)
        q[kf] = *(const f16x8*)(qsT + ((size_t)rt_q * 8 + kf) * 512 + lofs);

    const _Float16* kB = kT + ((size_t)(b * 128 + sk * 32) * 8) * 512 + lofs;
    const _Float16* vB = vT + ((size_t)(b * 16) * 64 + sk * 16) * 512 + lofs;

    f32x4 O[16];
#pragma unroll
    for (int dt = 0; dt < 16; dt++) O[dt] = (f32x4){0.f, 0.f, 0.f, 0.f};
    float ps[4] = {0.f, 0.f, 0.f, 0.f};

    for (int sub = 0; sub < 8; sub++) {
#pragma unroll
        for (int st = 0; st < 4; st++) {
            f32x4 c = {0.f, 0.f, 0.f, 0.f};
#pragma unroll
            for (int kf = 0; kf < 8; kf++)
                c = MFMA16(q[kf], *(const f16x8*)(kB + ((size_t)(sub * 4 + st) * 8 + kf) * 512), c);
#pragma unroll
            for (int reg = 0; reg < 4; reg++) {
                float p = __expf(fminf(c[reg], 10.5f));
                ps[reg] += p;
                wlds[(quad * 4 + reg) * 72 + st * 16 + l15] = (_Float16)p;
            }
        }
        f16x8 xp[2];
#pragma unroll
        for (int kf = 0; kf < 2; kf++)
            xp[kf] = *(const f16x8*)(wlds + l15 * 72 + kf * 32 + quad * 8);
#pragma unroll
        for (int dt = 0; dt < 16; dt++) {
            const _Float16* vp = vB + ((size_t)dt * 64 + sub * 2) * 512;
            O[dt] = MFMA16(xp[0], *(const f16x8*)(vp), O[dt]);
            O[dt] = MFMA16(xp[1], *(const f16x8*)(vp + 512), O[dt]);
        }
    }

#pragma unroll
    for (int msk = 1; msk <= 8; msk <<= 1)
#pragma unroll
        for (int reg = 0; reg < 4; reg++) ps[reg] += __shfl_xor(ps[reg], msk, 64);
    if (l15 == 0) {
#pragma unroll
        for (int reg = 0; reg < 4; reg++)
            psum4[(size_t)sk * 16384 + gr0 + quad * 4 + reg] = ps[reg];
    }

    // O transpose via per-wave LDS, coalesced row-major store
#pragma unroll
    for (int dt = 0; dt < 16; dt++)
#pragma unroll
        for (int reg = 0; reg < 4; reg++)
            wlds[(quad * 4 + reg) * 264 + dt * 16 + l15] = (_Float16)O[dt][reg];
#pragma unroll
    for (int j = 0; j < 8; j++) {
        int u = lane + j * 64;
        int row = u >> 5, col8 = u & 31;
        *(f16x8*)(Opart + ((size_t)sk * 16384 + gr0 + row) * 256 + col8 * 8) =
            *(const f16x8*)(wlds + row * 264 + col8 * 8);
    }
}

// ---------------------------------------------------------------------------
// LN: y = slots + (sum Opart)/(sum psum); x1=LN1 -> slots; LN2(x1) -> hT tiled
// ---------------------------------------------------------------------------
__global__ __launch_bounds__(256) void ln_k(
    const _Float16* __restrict__ Opart, const float* __restrict__ psum4,
    float* __restrict__ slots, _Float16* __restrict__ hT,
    const float* __restrict__ ln1_g, const float* __restrict__ ln1_b,
    const float* __restrict__ ln2_g, const float* __restrict__ ln2_b)
{
    const int tid = threadIdx.x, lane = tid & 63, wv = tid >> 6;
    const int row = blockIdx.x * 4 + wv;
    float l = 0.f;
#pragma unroll
    for (int j = 0; j < 4; j++) l += psum4[(size_t)j * 16384 + row];
    float invl = 1.f / l;
    float4 o4 = {0.f, 0.f, 0.f, 0.f};
#pragma unroll
    for (int j = 0; j < 4; j++) {
        f16x4 p = *(const f16x4*)(Opart + ((size_t)j * 16384 + row) * 256 + lane * 4);
        o4.x += (float)p[0]; o4.y += (float)p[1]; o4.z += (float)p[2]; o4.w += (float)p[3];
    }
    float4 s4 = *(const float4*)(slots + (size_t)row * 256 + lane * 4);
    float4 y;
    y.x = s4.x + o4.x * invl; y.y = s4.y + o4.y * invl;
    y.z = s4.z + o4.z * invl; y.w = s4.w + o4.w * invl;

    float sm = y.x + y.y + y.z + y.w, sq = dot4f(y, y);
#pragma unroll
    for (int m = 1; m < 64; m <<= 1) { sm += __shfl_xor(sm, m, 64); sq += __shfl_xor(sq, m, 64); }
    float mean = sm * (1.f / 256.f);
    float rstd = rsqrtf(sq * (1.f / 256.f) - mean * mean + 1e-5f);
    float4 g1 = *(const float4*)(ln1_g + lane * 4);
    float4 b1 = *(const float4*)(ln1_b + lane * 4);
    float4 x1;
    x1.x = (y.x - mean) * rstd * g1.x + b1.x;
    x1.y = (y.y - mean) * rstd * g1.y + b1.y;
    x1.z = (y.z - mean) * rstd * g1.z + b1.z;
    x1.w = (y.w - mean) * rstd * g1.w + b1.w;
    *(float4*)(slots + (size_t)row * 256 + lane * 4) = x1;

    float sm2 = x1.x + x1.y + x1.z + x1.w, sq2 = dot4f(x1, x1);
#pragma unroll
    for (int m = 1; m < 64; m <<= 1) { sm2 += __shfl_xor(sm2, m, 64); sq2 += __shfl_xor(sq2, m, 64); }
    float mean2 = sm2 * (1.f / 256.f);
    float rstd2 = rsqrtf(sq2 * (1.f / 256.f) - mean2 * mean2 + 1e-5f);
    float4 g2 = *(const float4*)(ln2_g + lane * 4);
    float4 b2 = *(const float4*)(ln2_b + lane * 4);
    f16x4 h;
    h[0] = (_Float16)((x1.x - mean2) * rstd2 * g2.x + b2.x);
    h[1] = (_Float16)((x1.y - mean2) * rstd2 * g2.y + b2.y);
    h[2] = (_Float16)((x1.z - mean2) * rstd2 * g2.z + b2.z);
    h[3] = (_Float16)((x1.w - mean2) * rstd2 * g2.w + b2.w);
    int d = lane * 4;
    *(f16x4*)(hT + ((size_t)(row >> 4) * 8 + (d >> 5)) * 512 + (row & 15) * 32
              + ((d >> 3) & 3) * 8 + (d & 7)) = h;
}

// ---------------------------------------------------------------------------
// FFN1: actT = gelu(h @ Wf1 + bf1), tiled. grid 1024: rb=bx>>2, hq=bx&3
// ---------------------------------------------------------------------------
__global__ __launch_bounds__(256) void ffn1_k(
    const _Float16* __restrict__ hT, const _Float16* __restrict__ wf1T,
    const float* __restrict__ bf1, _Float16* __restrict__ actT)
{
    const int tid = threadIdx.x, lane = tid & 63, wv = tid >> 6;
    const int l15 = lane & 15, quad = lane >> 4;
    const int lofs = l15 * 32 + quad * 8;
    const int bx = blockIdx.x, rb = bx >> 2, hq = bx & 3;
    const int rt = rb * 4 + wv;

    f16x8 bh[8];
#pragma unroll
    for (int ks = 0; ks < 8; ks++)
        bh[ks] = *(const f16x8*)(hT + ((size_t)rt * 8 + ks) * 512 + lofs);
#pragma unroll 2
    for (int ht = 0; ht < 8; ht++) {
        int hti = hq * 8 + ht;
        f32x4 c = {0.f, 0.f, 0.f, 0.f};
#pragma unroll
        for (int ks = 0; ks < 8; ks++)
            c = MFMA16(*(const f16x8*)(wf1T + ((size_t)hti * 8 + ks) * 512 + lofs), bh[ks], c);
        float4 bb = *(const float4*)(bf1 + hti * 16 + quad * 4);
        f16x4 o;
#pragma unroll
        for (int reg = 0; reg < 4; reg++) {
            float xg = c[reg] + bb[reg];
            o[reg] = (_Float16)(0.5f * xg * (1.f + erff(xg * 0.70710678118654752f)));
        }
        *(f16x4*)(actT + ((size_t)rt * 16 + (hti >> 1)) * 512 + l15 * 32
                  + ((hti & 1) * 2 + (quad >> 1)) * 8 + (quad & 1) * 4) = o;
    }
}

// ---------------------------------------------------------------------------
// FFN2: slots = x1 + act @ Wf2 + bf2 (f32 row-major via LDS transpose)
//       + slotsT tiled f16. grid 1024: rb=bx>>2, dq=bx&3
// ---------------------------------------------------------------------------
__global__ __launch_bounds__(256) void ffn2_k(
    const _Float16* __restrict__ actT, const _Float16* __restrict__ wf2T,
    const float* __restrict__ bf2, float* __restrict__ slots,
    _Float16* __restrict__ slotsT)
{
    __shared__ float xbuf[4][16][68];
    const int tid = threadIdx.x, lane = tid & 63, wv = tid >> 6;
    const int l15 = lane & 15, quad = lane >> 4;
    const int lofs = l15 * 32 + quad * 8;
    const int bx = blockIdx.x, rb = bx >> 2, dq = bx & 3;
    const int rt = rb * 4 + wv;
    const int gr0 = rt * 16;
    const int rr = lane >> 2, c4 = lane & 3;

    // stage x1 (16 rows x 64 d) coalesced -> LDS
#pragma unroll
    for (int j2 = 0; j2 < 4; j2++)
        *(float4*)&xbuf[wv][rr][j2 * 16 + c4 * 4] =
            *(const float4*)(slots + (size_t)(gr0 + rr) * 256 + dq * 64 + j2 * 16 + c4 * 4);

    f32x4 c[4];
#pragma unroll
    for (int dt = 0; dt < 4; dt++) {
        float4 x4 = *(const float4*)&xbuf[wv][l15][dt * 16 + quad * 4];
        float4 bb = *(const float4*)(bf2 + (dq * 4 + dt) * 16 + quad * 4);
        c[dt] = (f32x4){x4.x + bb.x, x4.y + bb.y, x4.z + bb.z, x4.w + bb.w};
    }
    const _Float16* ap = actT + ((size_t)rt * 16) * 512 + lofs;
    for (int ks = 0; ks < 16; ks++) {
        f16x8 bfrag = *(const f16x8*)(ap + (size_t)ks * 512);
#pragma unroll
        for (int dt = 0; dt < 4; dt++)
            c[dt] = MFMA16(*(const f16x8*)(wf2T + ((size_t)(dq * 4 + dt) * 16 + ks) * 512 + lofs), bfrag, c[dt]);
    }
    // tiled f16 slots
#pragma unroll
    for (int dt = 0; dt < 4; dt++) {
        int dti = dq * 4 + dt;
        f16x4 o;
#pragma unroll
        for (int reg = 0; reg < 4; reg++) o[reg] = (_Float16)c[dt][reg];
        *(f16x4*)(slotsT + ((size_t)rt * 8 + (dti >> 1)) * 512 + l15 * 32
                  + ((dti & 1) * 2 + (quad >> 1)) * 8 + (quad & 1) * 4) = o;
    }
    // f32 slots via LDS transpose (wave-local)
#pragma unroll
    for (int dt = 0; dt < 4; dt++) {
        float4 t = {c[dt][0], c[dt][1], c[dt][2], c[dt][3]};
        *(float4*)&xbuf[wv][l15][dt * 16 + quad * 4] = t;
    }
#pragma unroll
    for (int j2 = 0; j2 < 4; j2++)
        *(float4*)(slots + (size_t)(gr0 + rr) * 256 + dq * 64 + j2 * 16 + c4 * 4) =
            *(const float4*)&xbuf[wv][rr][j2 * 16 + c4 * 4];
}

// ---------------------------------------------------------------------------
// final scoring: wave per (b, i)
// ---------------------------------------------------------------------------
__global__ __launch_bounds__(256) void final_k(
    const float* __restrict__ slots, const float* __restrict__ qn,
    const float* __restrict__ clsn,
    const float* __restrict__ alphap, const float* __restrict__ tempp,
    float* __restrict__ out)
{
    const int tid = threadIdx.x, lane = tid & 63, wv = tid >> 6;
    const int bx = blockIdx.x;
    const int b = bx & 31, ig = bx >> 5;
    const int i = ig * 4 + wv;

    float4 qv = *(const float4*)(qn + (size_t)i * 256 + lane * 4);
    float4 xs[4];
    float st4[4];
#pragma unroll
    for (int n = 0; n < 4; n++) {
        xs[n] = *(const float4*)(slots + ((size_t)b * 512 + i * 4 + n) * 256 + lane * 4);
        float ss = dot4f(xs[n], xs[n]);
        float sq = dot4f(xs[n], qv);
#pragma unroll
        for (int m = 1; m < 64; m <<= 1) { ss += __shfl_xor(ss, m, 64); sq += __shfl_xor(sq, m, 64); }
        st4[n] = sq / fmaxf(sqrtf(ss), 1e-12f);
    }
    float mx = fmaxf(fmaxf(st4[0], st4[1]), fmaxf(st4[2], st4[3]));
    float e0 = __expf(st4[0] - mx), e1 = __expf(st4[1] - mx);
    float e2 = __expf(st4[2] - mx), e3 = __expf(st4[3] - mx);
    float inv = 1.f / (e0 + e1 + e2 + e3);
    float4 smv;
    smv.x = (e0 * xs[0].x + e1 * xs[1].x + e2 * xs[2].x + e3 * xs[3].x) * inv;
    smv.y = (e0 * xs[0].y + e1 * xs[1].y + e2 * xs[2].y + e3 * xs[3].y) * inv;
    smv.z = (e0 * xs[0].z + e1 * xs[1].z + e2 * xs[2].z + e3 * xs[3].z) * inv;
    smv.w = (e0 * xs[0].w + e1 * xs[1].w + e2 * xs[2].w + e3 * xs[3].w) * inv;
    float ssm = dot4f(smv, smv);
    float sqn = dot4f(smv, qv);
    float4 cv = *(const float4*)(clsn + (size_t)b * 256 + lane * 4);
    float cq = dot4f(cv, qv);
#pragma unroll
    for (int m = 1; m < 64; m <<= 1) {
        ssm += __shfl_xor(ssm, m, 64);
        sqn += __shfl_xor(sqn, m, 64);
        cq  += __shfl_xor(cq,  m, 64);
    }
    if (lane == 0) {
        float score = cq + alphap[0] * sqn / fmaxf(sqrtf(ssm), 1e-12f);
        out[(size_t)b * NI + i] = score / fmaxf(tempp[0], 1e-4f);
    }
}

// ---------------------------------------------------------------------------
extern "C" void kernel_launch(void* const* d_in, const int* in_sizes, int n_in,
                              void* d_out, int out_size, void* d_ws, size_t ws_size,
                              hipStream_t stream)
{
    const float* tokens     = (const float*)d_in[0];
    const float* cls_embed  = (const float*)d_in[1];
    const float* intent_q   = (const float*)d_in[2];
    const float* noise      = (const float*)d_in[3];
    const float* Wk  = (const float*)d_in[4];
    const float* bk  = (const float*)d_in[5];
    const float* Wv  = (const float*)d_in[6];
    const float* bv  = (const float*)d_in[7];
    const float* Wqs = (const float*)d_in[8];
    const float* bqs = (const float*)d_in[9];
    const float* Wqi = (const float*)d_in[10];
    const float* bqi = (const float*)d_in[11];
    const float* ln1g = (const float*)d_in[12];
    const float* ln1b = (const float*)d_in[13];
    const float* ln2g = (const float*)d_in[14];
    const float* ln2b = (const float*)d_in[15];
    const float* Wf1 = (const float*)d_in[16];
    const float* bf1 = (const float*)d_in[17];
    const float* Wf2 = (const float*)d_in[18];
    const float* bf2 = (const float*)d_in[19];
    const float* slot_mu    = (const float*)d_in[20];
    const float* slot_sigma = (const float*)d_in[21];
    const float* alphap = (const float*)d_in[22];
    const float* tempp  = (const float*)d_in[23];
    float* out = (float*)d_out;

    char* base = (char*)d_ws;
    // region A: tokT [0,33.5MB) during projection; then qsT | slotsT | hT
    _Float16* tokT  = (_Float16*)(base);
    _Float16* qsT   = (_Float16*)(base);                        //  8388608 B
    _Float16* slotsT= (_Float16*)(base + 8388608u);             //  8388608 B
    _Float16* hT    = (_Float16*)(base + 25165824u);            //  8388608 B
    _Float16* kT    = (_Float16*)(base + 33554432u);            // 33554432 B
    _Float16* vT    = (_Float16*)(base + 67108864u);            // 33554432 B
    _Float16* Opart = (_Float16*)(base + 100663296u);           // 33554432 B (aliases actT)
    _Float16* actT  = (_Float16*)(base + 100663296u);           // 16777216 B
    float* slots    = (float*)(base + 134217728u);              // 16777216 B
    _Float16* wkT   = (_Float16*)(base + 150994944u);           //   131072 B
    _Float16* wvT   = (_Float16*)(base + 151126016u);
    _Float16* wqsT  = (_Float16*)(base + 151257088u);
    _Float16* wf1T  = (_Float16*)(base + 151388160u);           //   262144 B
    _Float16* wf2T  = (_Float16*)(base + 151650304u);           //   262144 B
    float* qint2    = (float*)(base + 151912448u);              //   131072 B
    float* qnb      = (float*)(base + 152043520u);              //   131072 B
    float* clsn     = (float*)(base + 152174592u);              //    32768 B
    float* psum4    = (float*)(base + 152207360u);              //   262144 B

    tok_convert<<<8192, 256, 0, stream>>>(tokens, tokT);
    prep<<<272, 256, 0, stream>>>(Wk, Wv, Wqs, Wf1, Wf2, intent_q, Wqi, bqi, bqs,
                                  cls_embed, wkT, wvT, wqsT, wf1T, wf2T,
                                  qint2, qnb, clsn);
    kv_proj<<<4096, 64, 0, stream>>>(tokT, wkT, wvT, bk, bv, kT, vT);
    slots_init<<<2048, 256, 0, stream>>>(noise, slot_mu, slot_sigma, slots, slotsT);

    for (int it = 0; it < 3; it++) {
        qslot_k<<<1024, 256, 0, stream>>>(slotsT, wqsT, qint2, qsT);
        attn_k<<<1024, 256, 0, stream>>>(qsT, kT, vT, Opart, psum4);
        ln_k<<<4096, 256, 0, stream>>>(Opart, psum4, slots, hT, ln1g, ln1b, ln2g, ln2b);
        ffn1_k<<<1024, 256, 0, stream>>>(hT, wf1T, bf1, actT);
        ffn2_k<<<1024, 256, 0, stream>>>(actT, wf2T, bf2, slots, slotsT);
    }
    final_k<<<1024, 256, 0, stream>>>(slots, qnb, clsn, alphap, tempp, out);
}